// Round 11
// baseline (109.564 us; speedup 1.0000x reference)
//
#include <hip/hip_runtime.h>
#include <hip/hip_bf16.h>

typedef short bf16x8 __attribute__((ext_vector_type(8)));
typedef float f32x4 __attribute__((ext_vector_type(4)));

#define B_ROWS 8192
#define DIM 128
#define NCLS 512
#define MMAX 64
#define NSLICE 64
#define NPAIR 2080   // 64*65/2 pair-tiles of 128x128

// gamma * log2(e): logits computed in base-2 throughout
#define G2 369.32993f
// l - 64 bias folded in: exp2(l-64); values in [2^-87, 2^56]
#define G2D16B 87.083121f
#define LN2F 0.69314718056f

// ============ K1: prep + positives =========================================
// blocks [0,512): block T normalizes rows [16T,16T+16) -> PACKED bf16
//   fragment layout (verified, unchanged since R4).
// blocks [512,1024): class c = bid-512: 4-wave ballot scan members, fp32
//   normalize into LDS, exact fp32 positive/same-class LSEs (proven R5+R10).
__global__ __launch_bounds__(256) void prep_k(const float* __restrict__ feat,
                                              const int* __restrict__ label,
                                              unsigned int* __restrict__ fbp,
                                              float* __restrict__ lse2_p,
                                              float* __restrict__ lse2_same,
                                              int* __restrict__ ctrl) {
    const int bid = blockIdx.x;
    const int tid = threadIdx.x;

    if (bid < 512) {
        if (bid == 0 && tid < 4) ctrl[tid] = 0;  // ticket, gsum, gcnt, spare
        const int T = bid;
        const int rr = tid >> 4, q = tid & 15;
        const int row = T * 16 + rr;
        const float4* f4 = (const float4*)(feat + row * DIM + q * 8);
        const float4 v0 = f4[0], v1 = f4[1];
        float ss = v0.x * v0.x + v0.y * v0.y + v0.z * v0.z + v0.w * v0.w
                 + v1.x * v1.x + v1.y * v1.y + v1.z * v1.z + v1.w * v1.w;
        #pragma unroll
        for (int d = 1; d < 16; d <<= 1) ss += __shfl_xor(ss, d);  // 16-lane row group
        const float inv = 1.0f / fmaxf(sqrtf(ss), 1e-12f);
        const float e[8] = {v0.x, v0.y, v0.z, v0.w, v1.x, v1.y, v1.z, v1.w};
        unsigned int w[4];
        #pragma unroll
        for (int j = 0; j < 4; ++j) {
            __hip_bfloat16 lo = __float2bfloat16(e[2 * j] * inv);
            __hip_bfloat16 hi = __float2bfloat16(e[2 * j + 1] * inv);
            w[j] = (unsigned int)*(unsigned short*)&lo |
                   ((unsigned int)*(unsigned short*)&hi << 16);
        }
        const int g = (T * 4 + (q >> 2)) * 256 + (q & 3) * 64 + rr * 4;
        *(uint4*)(fbp + g) = make_uint4(w[0], w[1], w[2], w[3]);
        return;
    }

    // ---- positives: class c; 4-wave ballot scan + fp32-exact LSEs ----
    const int c = bid - 512;
    const int wv = tid >> 6, ln = tid & 63;
    __shared__ float F[MMAX][DIM + 1];
    __shared__ int rlw[4][MMAX];
    __shared__ int rl[MMAX];
    __shared__ int cntw[4];
    {
        int cnt = 0;
        #pragma unroll 1
        for (int it = 0; it < 8; ++it) {
            const int4 L = ((const int4*)label)[wv * 512 + it * 64 + ln];
            const int lv[4] = {L.x, L.y, L.z, L.w};
            #pragma unroll
            for (int j = 0; j < 4; ++j) {
                const bool hit = (lv[j] == c);
                const unsigned long long mask = __ballot(hit);
                const int below = __popcll(mask & ((1ull << ln) - 1ull));
                const int slot = cnt + below;
                if (hit && slot < MMAX) rlw[wv][slot] = wv * 2048 + it * 256 + ln * 4 + j;
                cnt += __popcll(mask);
            }
        }
        if (ln == 0) cntw[wv] = cnt;
    }
    __syncthreads();
    const int c0 = cntw[0], c1 = cntw[1], c2 = cntw[2], c3 = cntw[3];
    const int total = c0 + c1 + c2 + c3;
    const int m = total < MMAX ? total : MMAX;
    if (m == 0) return;
    const bool row_valid = (total >= 2) && (total < B_ROWS);
    {
        const int offs = (wv > 0 ? c0 : 0) + (wv > 1 ? c1 : 0) + (wv > 2 ? c2 : 0);
        const int mycnt = cntw[wv] < MMAX ? cntw[wv] : MMAX;
        if (ln < mycnt) {
            const int slot = offs + ln;
            if (slot < m) rl[slot] = rlw[wv][ln];
        }
    }
    __syncthreads();

    // fp32 normalize member rows into LDS (exact, matches reference)
    for (int i = wv; i < m; i += 4) {
        const int r = rl[i];
        const float2 v = ((const float2*)feat)[r * 64 + ln];
        float ss = v.x * v.x + v.y * v.y;
        #pragma unroll
        for (int d = 1; d < 64; d <<= 1) ss += __shfl_xor(ss, d);
        const float inv = 1.0f / fmaxf(sqrtf(ss), 1e-12f);
        F[i][2 * ln] = v.x * inv;
        F[i][2 * ln + 1] = v.y * inv;
    }
    __syncthreads();

    for (int i = wv; i < m; i += 4) {
        float s = 0.f;
        if (ln < m) {
            #pragma unroll 8
            for (int k = 0; k < DIM; ++k) s = fmaf(F[i][k], F[ln][k], s);
        }
        const bool act = (ln < m) && (ln != i);
        const float up = 1.25f - s;
        const float lp = act ? G2 * fmaxf(up, 0.f) * (up - 0.5f) : -1e30f;
        const float un = s + 0.25f;
        const float lnn = act ? G2 * fmaxf(un, 0.f) * (un - 0.5f) : -1e30f;
        float Mp = lp, Mn = lnn;
        #pragma unroll
        for (int d = 1; d < 64; d <<= 1) {
            Mp = fmaxf(Mp, __shfl_xor(Mp, d));
            Mn = fmaxf(Mn, __shfl_xor(Mn, d));
        }
        float Sp = act ? __builtin_amdgcn_exp2f(lp - Mp) : 0.f;
        float Sn = act ? __builtin_amdgcn_exp2f(lnn - Mn) : 0.f;
        #pragma unroll
        for (int d = 1; d < 64; d <<= 1) { Sp += __shfl_xor(Sp, d); Sn += __shfl_xor(Sn, d); }
        if (ln == 0) {
            const int row = rl[i];
            lse2_p[row]    = row_valid ? (Mp + __builtin_amdgcn_logf(Sp)) : -1e30f;
            lse2_same[row] = row_valid ? (Mn + __builtin_amdgcn_logf(Sn)) : -1e30f;
        }
    }
}

// e = exp2(l - 64), l = G2*(max(s,-1/4)^2 - 1/16); clamp biased exp at 56.
#define ELEM(sv) __builtin_amdgcn_exp2f(fminf(fmaf(fmaxf((sv), -0.25f) * fmaxf((sv), -0.25f), G2, -G2D16B), 56.f))

// ============ K2: pure symmetric pair-tile neg-sums =========================
// block = pair (I,J), I<=J, 128x128 sim tile computed ONCE.
//   row-side: rows of I summed over J-cols -> PR[J][r] (RAW biased sums)
//   col-side: (I<J) cols summed over I-rows via shfl -> PR[I][c]
// LDS = 2 KB only -> 8 blocks/CU resident; uniform grid, no tail.
__global__ __launch_bounds__(256, 4) void mega_k(const unsigned short* __restrict__ fb_,
                                                 float* __restrict__ PR) {
    __shared__ float colS[4][128];
    const int bid = blockIdx.x;
    const int tid = threadIdx.x;
    const int wv = tid >> 6, ln = tid & 63;

    // ---- decode pair (I,J), I<=J ----
    int I = (int)((129.0f - sqrtf(16641.0f - 8.0f * (float)bid)) * 0.5f);
    while (I * 64 - I * (I - 1) / 2 > bid) --I;
    while ((I + 1) * 64 - (I + 1) * I / 2 <= bid) ++I;
    const int J = I + (bid - (I * 64 - I * (I - 1) / 2));
    const bool offd = (I != J);

    const int lc = ln & 15, lg = ln >> 4;
    const int wv2 = wv * 2;
    const bf16x8* pk = (const bf16x8*)fb_;

    // A fragments: wave's 32 I-rows (2 row-tiles of 16)
    const int Ta0 = I * 8 + wv2;
    bf16x8 a0[4], a1[4];
    #pragma unroll
    for (int k = 0; k < 4; ++k) {
        a0[k] = pk[(Ta0 * 4 + k) * 64 + ln];
        a1[k] = pk[((Ta0 + 1) * 4 + k) * 64 + ln];
    }

    float Sr0 = 0.f, Sr1 = 0.f;
    bf16x8 bA[4], bB[4];
    const bf16x8* pB = pk + J * 2048 + ln;  // strength-reduced B base

    #define LOADB(dst, base) { \
        _Pragma("unroll") \
        for (int k = 0; k < 4; ++k) dst[k] = (base)[k * 64]; }

    #define STEP(bR, t) { \
        f32x4 acc0 = {0.f, 0.f, 0.f, 0.f}, acc1 = acc0; \
        _Pragma("unroll") \
        for (int k = 0; k < 4; ++k) { \
            acc0 = __builtin_amdgcn_mfma_f32_16x16x32_bf16(bR[k], a0[k], acc0, 0, 0, 0); \
            acc1 = __builtin_amdgcn_mfma_f32_16x16x32_bf16(bR[k], a1[k], acc1, 0, 0, 0); \
        } \
        float e00 = ELEM(acc0[0]), e01 = ELEM(acc0[1]); \
        float e02 = ELEM(acc0[2]), e03 = ELEM(acc0[3]); \
        float e10 = ELEM(acc1[0]), e11 = ELEM(acc1[1]); \
        float e12 = ELEM(acc1[2]), e13 = ELEM(acc1[3]); \
        if (!offd && (t) == wv2) { \
            const int base = lg * 4; \
            e00 = (base + 0 == lc) ? 0.f : e00; \
            e01 = (base + 1 == lc) ? 0.f : e01; \
            e02 = (base + 2 == lc) ? 0.f : e02; \
            e03 = (base + 3 == lc) ? 0.f : e03; \
        } \
        if (!offd && (t) == wv2 + 1) { \
            const int base = lg * 4; \
            e10 = (base + 0 == lc) ? 0.f : e10; \
            e11 = (base + 1 == lc) ? 0.f : e11; \
            e12 = (base + 2 == lc) ? 0.f : e12; \
            e13 = (base + 3 == lc) ? 0.f : e13; \
        } \
        Sr0 += (e00 + e01) + (e02 + e03); \
        Sr1 += (e10 + e11) + (e12 + e13); \
        if (offd) { \
            float c0 = e00 + e10, c1 = e01 + e11; \
            float c2 = e02 + e12, c3 = e03 + e13; \
            _Pragma("unroll") \
            for (int d = 1; d < 16; d <<= 1) { \
                c0 += __shfl_xor(c0, d); c1 += __shfl_xor(c1, d); \
                c2 += __shfl_xor(c2, d); c3 += __shfl_xor(c3, d); \
            } \
            if (lc == 0) \
                *(float4*)&colS[wv][(t) * 16 + lg * 4] = make_float4(c0, c1, c2, c3); \
        } }

    LOADB(bA, pB);
    #pragma unroll 1
    for (int t = 0; t < 8; t += 2) {
        LOADB(bB, pB + 256);
        STEP(bA, t);
        if (t + 2 < 8) LOADB(bA, pB + 512);
        STEP(bB, t + 1);
        pB += 512;
    }
    #undef LOADB
    #undef STEP

    // row-side: merge lg groups (disjoint col subsets), write RAW sums
    #pragma unroll
    for (int d = 16; d < 64; d <<= 1) {
        Sr0 += __shfl_xor(Sr0, d);
        Sr1 += __shfl_xor(Sr1, d);
    }
    if (lg == 0) {
        const int r = I * 128 + wv * 32 + lc;
        PR[J * B_ROWS + r]      = Sr0;
        PR[J * B_ROWS + r + 16] = Sr1;
    }

    // col-side: merge the 4 waves' partial col sums, write RAW sums
    if (offd) {
        __syncthreads();
        if (tid < 128) {
            const float tot = colS[0][tid] + colS[1][tid] +
                              colS[2][tid] + colS[3][tid];
            PR[I * B_ROWS + J * 128 + tid] = tot;
        }
    }
}

// ============ K3: finalize — parallel raw-sum, one log2 per row =============
__global__ __launch_bounds__(256) void finalize_k(const float* __restrict__ PR,
                                                  const float* __restrict__ lse2_p,
                                                  const float* __restrict__ lse2_same,
                                                  int* __restrict__ ctrl,
                                                  float* __restrict__ out) {
    const int r = blockIdx.x * 256 + threadIdx.x;
    float local = 0.f; int c = 0;
    const float lp2 = lse2_p[r];
    if (lp2 > -1e29f) {
        float pa = 0.f, pb = 0.f, pc = 0.f, pd = 0.f;
        #pragma unroll
        for (int s = 0; s < NSLICE; s += 4) {
            pa += PR[(s + 0) * B_ROWS + r];
            pb += PR[(s + 1) * B_ROWS + r];
            pc += PR[(s + 2) * B_ROWS + r];
            pd += PR[(s + 3) * B_ROWS + r];
        }
        const float Sa = (pa + pb) + (pc + pd);
        const float lse2_all = __builtin_amdgcn_logf(Sa) + 64.f;  // unbias
        const float d = lse2_same[r] - lse2_all;
        const float corr = __builtin_amdgcn_logf(fmaxf(1.f - __builtin_amdgcn_exp2f(d), 1e-30f));
        const float z = LN2F * (lp2 + lse2_all + corr);
        local = fmaxf(z, 0.f) + log1pf(expf(-fabsf(z)));  // stable softplus
        c = 1;
    }
    #pragma unroll
    for (int d = 1; d < 64; d <<= 1) { local += __shfl_xor(local, d); c += __shfl_xor(c, d); }
    __shared__ float wsum[4];
    __shared__ int wcnt[4];
    const int wv = threadIdx.x >> 6;
    if ((threadIdx.x & 63) == 0) { wsum[wv] = local; wcnt[wv] = c; }
    __syncthreads();
    if (threadIdx.x == 0) {
        const float ts = wsum[0] + wsum[1] + wsum[2] + wsum[3];
        const int tc = wcnt[0] + wcnt[1] + wcnt[2] + wcnt[3];
        atomicAdd((float*)&ctrl[1], ts);
        atomicAdd(&ctrl[2], tc);
        __threadfence();
        const int ticket = atomicAdd(&ctrl[0], 1);
        if (ticket == (int)gridDim.x - 1) {
            const float gs = atomicAdd((float*)&ctrl[1], 0.0f);
            const int gc = atomicAdd(&ctrl[2], 0);
            out[0] = gs / (float)(gc > 1 ? gc : 1);
        }
    }
}

// ---------------- launch ----------------------------------------------------
extern "C" void kernel_launch(void* const* d_in, const int* in_sizes, int n_in,
                              void* d_out, int out_size, void* d_ws, size_t ws_size,
                              hipStream_t stream) {
    const float* feat = (const float*)d_in[0];
    const int* label = (const int*)d_in[1];
    float* out = (float*)d_out;
    char* ws = (char*)d_ws;

    unsigned int* fbp = (unsigned int*)(ws);                  // 2 MB packed bf16
    float* PR         = (float*)(ws + (2u << 20));            // 64*8192*4 = 2 MB
    float* lse2_p     = (float*)(ws + (4u << 20));            // 32 KB
    float* lse2_same  = (float*)(ws + (4u << 20) + 32768);    // 32 KB
    int*   ctrl       = (int*)  (ws + (4u << 20) + 65536);    // 16 B

    prep_k<<<1024, 256, 0, stream>>>(feat, label, fbp, lse2_p, lse2_same, ctrl);
    mega_k<<<NPAIR, 256, 0, stream>>>((const unsigned short*)fbp, PR);
    finalize_k<<<B_ROWS / 256, 256, 0, stream>>>(PR, lse2_p, lse2_same, ctrl, out);
}